// Round 9
// baseline (691.819 us; speedup 1.0000x reference)
//
#include <hip/hip_runtime.h>

#define NB 256   // batch
#define NS 256   // seq len == number of steps
#define NE 2     // encoder dim
#define ND 128   // decoder dim
#define NBB 16   // batches per block  -> 16 blocks
#define NT 512   // threads per block (8 waves)
#define NN 16    // Chebyshev nodes/degree for the h -> context map
#define SLOTH 136 // halfs per batch row in the h buffer (128 + 8 pad)
#define XSLOT 36  // floats per batch row in the xpart buffer (16 float2 + pad)

typedef float vf4 __attribute__((ext_vector_type(4)));
typedef _Float16 f16x8 __attribute__((ext_vector_type(8)));
typedef _Float16 f16x4 __attribute__((ext_vector_type(4)));
typedef float f32x4 __attribute__((ext_vector_type(4)));

constexpr float L2E = 1.4426950408889634f;  // log2(e)
constexpr float PI_F = 3.14159265358979323846f;

// Monomial coefficients of Chebyshev T_k: T_k(h) = sum_m CT[k][m] h^m (exact ints).
__device__ const float CT[16][16] = {
 {1,0,0,0,0,0,0,0,0,0,0,0,0,0,0,0},
 {0,1,0,0,0,0,0,0,0,0,0,0,0,0,0,0},
 {-1,0,2,0,0,0,0,0,0,0,0,0,0,0,0,0},
 {0,-3,0,4,0,0,0,0,0,0,0,0,0,0,0,0},
 {1,0,-8,0,8,0,0,0,0,0,0,0,0,0,0,0},
 {0,5,0,-20,0,16,0,0,0,0,0,0,0,0,0,0},
 {-1,0,18,0,-48,0,32,0,0,0,0,0,0,0,0,0},
 {0,-7,0,56,0,-112,0,64,0,0,0,0,0,0,0,0},
 {1,0,-32,0,160,0,-256,0,128,0,0,0,0,0,0,0},
 {0,9,0,-120,0,432,0,-576,0,256,0,0,0,0,0},
 {-1,0,50,0,-400,0,1120,0,-1280,0,512,0,0,0,0,0},
 {0,-11,0,220,0,-1232,0,2816,0,-2816,0,1024,0,0,0,0},
 {1,0,-72,0,840,0,-3584,0,6912,0,-6144,0,2048,0,0,0},
 {0,13,0,-364,0,2912,0,-9984,0,16640,0,-13312,0,4096,0,0},
 {-1,0,98,0,-1568,0,9408,0,-26880,0,39424,0,-28672,0,8192,0},
 {0,-15,0,560,0,-6048,0,28800,0,-70400,0,92160,0,-61440,0,16384}};

// DPP add: x + dpp_move(x). All-VALU cross-lane.
template <int C>
__device__ __forceinline__ float dppadd(float x) {
    return x + __builtin_bit_cast(float,
        __builtin_amdgcn_update_dpp(0, __builtin_bit_cast(int, x), C, 0xF, 0xF, true));
}
__device__ __forceinline__ float red_wave64(float x) {    // valid in lane 63
    x = dppadd<0xB1>(x); x = dppadd<0x4E>(x); x = dppadd<0x141>(x);
    x = dppadd<0x140>(x); x = dppadd<0x142>(x); x = dppadd<0x143>(x); return x;
}

// 16 batches per block, 16 blocks. The gate matvec is a REAL matmul:
// C[512 gate-rows x 16 batches] = Whh(A) . h^T(B), 128 MFMA/block-step for
// 16 batches (vs 128/batch with the old broadcast-A scheme -- the A operand
// finally carries 16 useful rows). Orientation chosen for locality:
//   A = W fragment: lane holds A[m = nib][k = 8*grp+e]  (tile rows = gate
//       rows 128*j + 16*wave + [0,16), j = gate)          [mirror of the
//       B-layout verified in rounds 1-8]
//   B = h: lane holds B[k = 8*grp+e][n = nib] = h[batch nib][k]
//   C: row m = 4*grp+jj (ch = 16*wave+4*grp+jj), col n = nib (batch)
// => each lane owns ONE batch (nib) x 4 channels x ALL 4 gates: pointwise,
// c-state, per-batch poly coeffs (32 VGPR, batch=nib) all lane-local.
// x-partials cross waves via plain xpart[batch][16 slots] stores (xor16
// ds_swizzle pre-reduce), summed by consumers at the next step head in the
// shadow of the MFMA. ONE barrier per step; out stores fire-and-forget
// (vmcnt never drained in-loop).
__global__ __launch_bounds__(NT, 2)
void attn_lstm_decoder(const float* __restrict__ enc,   // [B,S,E]
                       const float* __restrict__ W1w,   // [S,S]
                       const float* __restrict__ W1b,   // [S]
                       const float* __restrict__ W2w,   // [S,2S]
                       const float* __restrict__ W2b,   // [S]
                       const float* __restrict__ Wih,   // [4D,E]
                       const float* __restrict__ Whh,   // [4D,D]
                       const float* __restrict__ bih,   // [4D]
                       const float* __restrict__ bhh,   // [4D]
                       float* __restrict__ out)         // [S,B,D]
{
    const int b0   = blockIdx.x * NBB;    // first batch of this block
    const int t    = threadIdx.x;
    const int wave = t >> 6;              // 0..7
    const int lane = t & 63;
    const int grp  = lane >> 4;           // 0..3: MFMA k-group
    const int nib  = lane & 15;           // batch index within the block
    const int chb  = 16 * wave + 4 * grp; // lane's channel base (+jj, jj=0..3)

    __shared__ __align__(16) _Float16 hist16[2 * NBB * SLOTH]; // h dbuf (f16)
    __shared__ __align__(16) float    xp[2 * NBB * XSLOT];     // x partials dbuf
    __shared__ float e0_l[NBB * NS];
    __shared__ float e1_l[NBB * NS];
    __shared__ float A2_l[NBB * NS];
    __shared__ float g2_l[NS];
    __shared__ float Ml[NN * NN];
    __shared__ float2 Pn2[NN * NBB];
    __shared__ float2 Vl2[NN * NBB];
    __shared__ float Pm0[NBB * NN], Pm1[NBB * NN];

    // ---------------- setup (once per block) ----------------
    #pragma unroll
    for (int bi = 0; bi < NBB; ++bi) {
        float v = enc[(size_t)(b0 + bi) * (NS * NE) + t];   // coalesced
        if (t & 1) e1_l[bi * NS + (t >> 1)] = v; else e0_l[bi * NS + (t >> 1)] = v;
    }
    if (t < NN * NN) {
        const int mi = t >> 4, mj = t & 15;
        const float w = (mi == 0) ? (1.0f / NN) : (2.0f / NN);
        Ml[t] = w * __cosf((float)(mi * (2 * mj + 1)) * (PI_F / (2 * NN)));
    }
    __syncthreads();

    // w1sum rows (batch-independent): 32 rows per wave.
    for (int r = 0; r < 32; ++r) {
        const int s = wave * 32 + r;
        float p = W1w[s * NS + lane]       + W1w[s * NS + lane + 64]
                + W1w[s * NS + lane + 128] + W1w[s * NS + lane + 192];
        p = red_wave64(p);
        if (lane == 63) g2_l[s] = p * (2.0f * L2E);
    }

    // w2term per batch: A2[bi][s]. Thread (bi = t>>5, si = t&31) does 8 rows.
    {
        const int bi = t >> 5;
        const int si = t & 31;
        for (int r = 0; r < 8; ++r) {
            const int s = si + 32 * r;
            const vf4* w4 = reinterpret_cast<const vf4*>(W2w + (size_t)s * (2 * NS));
            float qq = 0.0f;
            for (int c4 = 0; c4 < NS / 2; ++c4) {
                const vf4 wv = w4[c4];
                qq = fmaf(e0_l[bi * NS + 2 * c4],     wv.x, qq);
                qq = fmaf(e1_l[bi * NS + 2 * c4],     wv.y, qq);
                qq = fmaf(e0_l[bi * NS + 2 * c4 + 1], wv.z, qq);
                qq = fmaf(e1_l[bi * NS + 2 * c4 + 1], wv.w, qq);
            }
            A2_l[bi * NS + s] = (qq + W2b[s] + W1b[s]) * (2.0f * L2E);
        }
    }
    __syncthreads();

    // Node softmax per (node, batch): 256 threads, full s-loop each.
    if (t < NN * NBB) {
        const int jn = t >> 4, bi = t & 15;
        const float y  = __cosf((float)(2 * jn + 1) * (PI_F / (2 * NN)));
        const float C2 = -2.0f * L2E;
        float l = 0.0f, p0 = 0.0f, p1 = 0.0f;
        for (int s = 0; s < NS; ++s) {
            const float m1 = fmaf(y, g2_l[s], A2_l[bi * NS + s]);
            const float u  = __builtin_amdgcn_exp2f(m1);
            const float rc = __builtin_amdgcn_rcpf(u + 1.0f);
            const float e  = __builtin_amdgcn_exp2f(rc * C2);
            l += e;
            p0 = fmaf(e, e0_l[bi * NS + s], p0);
            p1 = fmaf(e, e1_l[bi * NS + s], p1);
        }
        const float rl = __builtin_amdgcn_rcpf(l);
        Pn2[jn * NBB + bi] = make_float2(p0 * rl, p1 * rl);
    }
    __syncthreads();

    // DCT collapse per batch: V[i][bi], 1/ND folded in.
    if (t < NN * NBB) {
        const int i = t >> 4, bi = t & 15;
        float v0 = 0.0f, v1 = 0.0f;
        #pragma unroll
        for (int j = 0; j < NN; ++j) {
            v0 = fmaf(Ml[i * NN + j], Pn2[j * NBB + bi].x, v0);
            v1 = fmaf(Ml[i * NN + j], Pn2[j * NBB + bi].y, v1);
        }
        Vl2[i * NBB + bi] = make_float2(v0 * (1.0f / ND), v1 * (1.0f / ND));
    }
    __syncthreads();

    // Chebyshev -> monomial per batch: Pm[bi][m].
    if (t < NN * NBB) {
        const int m = t >> 4, bi = t & 15;
        float s0 = 0.0f, s1 = 0.0f;
        #pragma unroll
        for (int k = 0; k < NN; ++k) {
            s0 = fmaf(Vl2[k * NBB + bi].x, CT[k][m], s0);
            s1 = fmaf(Vl2[k * NBB + bi].y, CT[k][m], s1);
        }
        Pm0[bi * NN + m] = s0; Pm1[bi * NN + m] = s1;
    }

    // Whh A-fragments: tile j (= gate) covers rows 128*j + 16*wave + [0,16).
    // Lane holds A[m=nib][k=8*grp+e] (k = 32*kt + 8*grp + e within kt-slice).
    f16x8 wf[4][4];
    #pragma unroll
    for (int j = 0; j < 4; ++j) {
        const int row = 128 * j + 16 * wave + nib;
        #pragma unroll
        for (int kt = 0; kt < 4; ++kt) {
            const vf4 wa = *reinterpret_cast<const vf4*>(Whh + row * ND + 32 * kt + 8 * grp);
            const vf4 wb = *reinterpret_cast<const vf4*>(Whh + row * ND + 32 * kt + 8 * grp + 4);
            f16x8 wv;
            wv[0] = (_Float16)wa.x; wv[1] = (_Float16)wa.y;
            wv[2] = (_Float16)wa.z; wv[3] = (_Float16)wa.w;
            wv[4] = (_Float16)wb.x; wv[5] = (_Float16)wb.y;
            wv[6] = (_Float16)wb.z; wv[7] = (_Float16)wb.w;
            wf[j][kt] = wv;
        }
    }
    // Wih / bias constants for this lane's 4 channels (chb+jj), all gates.
    float wi0_[4][4], wi1_[4][4], bb_[4][4];
    #pragma unroll
    for (int j = 0; j < 4; ++j) {
        #pragma unroll
        for (int jj = 0; jj < 4; ++jj) {
            const int r = 128 * j + chb + jj;
            wi0_[j][jj] = Wih[r * 2 + 0];
            wi1_[j][jj] = Wih[r * 2 + 1];
            bb_[j][jj]  = bih[r] + bhh[r];
        }
    }

    // zero both h buffers
    for (int i = t; i < 2 * NBB * SLOTH; i += NT) hist16[i] = (_Float16)0.0f;
    float c_[4] = {0.f, 0.f, 0.f, 0.f};
    __syncthreads();                     // Pm visible

    // Per-lane poly coefficients for batch nib (monomial, both encoder dims).
    float cc0[16], cc1[16];
    #pragma unroll
    for (int m = 0; m < NN; ++m) {
        cc0[m] = Pm0[nib * NN + m];
        cc1[m] = Pm1[nib * NN + m];
    }

    // G eval (even/odd Horner, degree 15), accumulates into (a0, a1).
    auto evalG2 = [&](float h, float& a0, float& a1) {
        const float h2 = h * h;
        float e0v = cc0[14], o0v = cc0[15];
        float e1v = cc1[14], o1v = cc1[15];
        #pragma unroll
        for (int k = 12; k >= 0; k -= 2) {
            e0v = fmaf(e0v, h2, cc0[k]);
            o0v = fmaf(o0v, h2, cc0[k + 1]);
            e1v = fmaf(e1v, h2, cc1[k]);
            o1v = fmaf(o1v, h2, cc1[k + 1]);
        }
        a0 += fmaf(h, o0v, e0v);
        a1 += fmaf(h, o1v, e1v);
    };

    // Prologue: x partials for step 0 (h = 0 -> G(0) = cc[0] per eval).
    {
        float p0 = 4.0f * cc0[0];
        float p1 = 4.0f * cc1[0];
        p0 += __builtin_bit_cast(float, __builtin_amdgcn_ds_swizzle(__builtin_bit_cast(int, p0), 0x401F));
        p1 += __builtin_bit_cast(float, __builtin_amdgcn_ds_swizzle(__builtin_bit_cast(int, p1), 0x401F));
        if (!(lane & 16)) {
            float2* xw = reinterpret_cast<float2*>(&xp[(0 * NBB + nib) * XSLOT]);
            xw[2 * wave + (lane >> 5)] = make_float2(p0, p1);
        }
    }
    __syncthreads();

    const size_t outbase = (size_t)(b0 + nib) * ND + chb;

    // ---------------- the recurrence (ONE barrier per step) ----------------
    for (int step = 0; step < NS; ++step) {
        const int pr = step & 1;
        const _Float16* hb = &hist16[(pr ^ 1) * NBB * SLOTH];

        // x for this lane's batch: sum 16 float2 partials (broadcast b128s,
        // hidden under the MFMA).
        const vf4* xr = reinterpret_cast<const vf4*>(&xp[(pr * NBB + nib) * XSLOT]);
        f32x4 xs = xr[0] + xr[1];
        xs += xr[2] + xr[3];
        xs += xr[4] + xr[5];
        xs += xr[6] + xr[7];
        const float x0 = xs[0] + xs[2];
        const float x1 = xs[1] + xs[3];

        // h B-fragments: lane reads h[batch nib][32*kt + 8*grp .. +8].
        f16x8 hf[4];
        #pragma unroll
        for (int kt = 0; kt < 4; ++kt)
            hf[kt] = __builtin_bit_cast(f16x8,
                *reinterpret_cast<const int4*>(hb + nib * SLOTH + 32 * kt + 8 * grp));

        // Gate matmul: 4 independent depth-4 chains (one per gate).
        f32x4 acc[4];
        #pragma unroll
        for (int j = 0; j < 4; ++j) {
            f32x4 a = {0.0f, 0.0f, 0.0f, 0.0f};
            a = __builtin_amdgcn_mfma_f32_16x16x32_f16(wf[j][0], hf[0], a, 0, 0, 0);
            a = __builtin_amdgcn_mfma_f32_16x16x32_f16(wf[j][1], hf[1], a, 0, 0, 0);
            a = __builtin_amdgcn_mfma_f32_16x16x32_f16(wf[j][2], hf[2], a, 0, 0, 0);
            a = __builtin_amdgcn_mfma_f32_16x16x32_f16(wf[j][3], hf[3], a, 0, 0, 0);
            acc[j] = a;
        }

        // Pointwise LSTM for 4 (batch=nib, ch=chb+jj) pairs -- all lane-local.
        float h_[4];
        #pragma unroll
        for (int jj = 0; jj < 4; ++jj) {
            const float gi = acc[0][jj] + fmaf(x0, wi0_[0][jj], fmaf(x1, wi1_[0][jj], bb_[0][jj]));
            const float gf = acc[1][jj] + fmaf(x0, wi0_[1][jj], fmaf(x1, wi1_[1][jj], bb_[1][jj]));
            const float gg = acc[2][jj] + fmaf(x0, wi0_[2][jj], fmaf(x1, wi1_[2][jj], bb_[2][jj]));
            const float go = acc[3][jj] + fmaf(x0, wi0_[3][jj], fmaf(x1, wi1_[3][jj], bb_[3][jj]));

            const float si = __builtin_amdgcn_rcpf(1.0f + __builtin_amdgcn_exp2f(-L2E * gi));
            const float sf = __builtin_amdgcn_rcpf(1.0f + __builtin_amdgcn_exp2f(-L2E * gf));
            const float so = __builtin_amdgcn_rcpf(1.0f + __builtin_amdgcn_exp2f(-L2E * go));
            const float tg = 1.0f - 2.0f * __builtin_amdgcn_rcpf(
                __builtin_amdgcn_exp2f(2.0f * L2E * gg) + 1.0f);
            c_[jj] = fmaf(sf, c_[jj], si * tg);
            const float tc2 = 1.0f - 2.0f * __builtin_amdgcn_rcpf(
                __builtin_amdgcn_exp2f(2.0f * L2E * c_[jj]) + 1.0f);
            h_[jj] = so * tc2;
        }

        // out store: 4 contiguous f32 (fire-and-forget, vmcnt never drained).
        *reinterpret_cast<vf4*>(out + (size_t)step * (NB * ND) + outbase) =
            *reinterpret_cast<const vf4*>(h_);

        // h f16 write: 4 contiguous halfs, one b64.
        {
            f16x4 hp;
            hp[0] = (_Float16)h_[0]; hp[1] = (_Float16)h_[1];
            hp[2] = (_Float16)h_[2]; hp[3] = (_Float16)h_[3];
            *reinterpret_cast<f16x4*>(&hist16[(pr * NBB + nib) * SLOTH + chb]) = hp;
        }

        // x partials for step+1: 4 G-evals + xor16 swizzle pre-reduce.
        {
            float p0 = 0.0f, p1 = 0.0f;
            evalG2(h_[0], p0, p1);
            evalG2(h_[1], p0, p1);
            evalG2(h_[2], p0, p1);
            evalG2(h_[3], p0, p1);
            p0 += __builtin_bit_cast(float, __builtin_amdgcn_ds_swizzle(__builtin_bit_cast(int, p0), 0x401F));
            p1 += __builtin_bit_cast(float, __builtin_amdgcn_ds_swizzle(__builtin_bit_cast(int, p1), 0x401F));
            if (!(lane & 16)) {
                float2* xw = reinterpret_cast<float2*>(&xp[((pr ^ 1) * NBB + nib) * XSLOT]);
                xw[2 * wave + (lane >> 5)] = make_float2(p0, p1);
            }
        }

        // LDS-only drain + raw barrier: global stores stay in flight.
        asm volatile("s_waitcnt lgkmcnt(0)" ::: "memory");
        __builtin_amdgcn_s_barrier();
    }
}

extern "C" void kernel_launch(void* const* d_in, const int* in_sizes, int n_in,
                              void* d_out, int out_size, void* d_ws, size_t ws_size,
                              hipStream_t stream) {
    const float* enc = (const float*)d_in[0];
    const float* W1w = (const float*)d_in[1];
    const float* W1b = (const float*)d_in[2];
    const float* W2w = (const float*)d_in[3];
    const float* W2b = (const float*)d_in[4];
    const float* Wih = (const float*)d_in[5];
    const float* Whh = (const float*)d_in[6];
    const float* bih = (const float*)d_in[7];
    const float* bhh = (const float*)d_in[8];
    attn_lstm_decoder<<<NB / NBB, NT, 0, stream>>>(enc, W1w, W1b, W2w, W2b,
                                                   Wih, Whh, bih, bhh, (float*)d_out);
}

// Round 10
// 354.872 us; speedup vs baseline: 1.9495x; 1.9495x over previous
//
#include <hip/hip_runtime.h>

#define NB 256   // batch
#define NS 256   // seq len == number of steps
#define NE 2     // encoder dim
#define ND 128   // decoder dim
#define NBB 2    // batches per block (independent halves) -> 128 blocks
#define NT 512   // threads per block (8 waves: 4 per batch half)
#define NN 16    // Chebyshev nodes/degree for the h -> context map

typedef float vf4 __attribute__((ext_vector_type(4)));
typedef _Float16 f16x8 __attribute__((ext_vector_type(8)));
typedef float f32x4 __attribute__((ext_vector_type(4)));

constexpr float L2E = 1.4426950408889634f;  // log2(e)
constexpr float PI_F = 3.14159265358979323846f;

// Monomial coefficients of Chebyshev T_k: T_k(h) = sum_m CT[k][m] h^m (exact ints).
__device__ const float CT[16][16] = {
 {1,0,0,0,0,0,0,0,0,0,0,0,0,0,0,0},
 {0,1,0,0,0,0,0,0,0,0,0,0,0,0,0,0},
 {-1,0,2,0,0,0,0,0,0,0,0,0,0,0,0,0},
 {0,-3,0,4,0,0,0,0,0,0,0,0,0,0,0,0},
 {1,0,-8,0,8,0,0,0,0,0,0,0,0,0,0,0},
 {0,5,0,-20,0,16,0,0,0,0,0,0,0,0,0,0},
 {-1,0,18,0,-48,0,32,0,0,0,0,0,0,0,0,0},
 {0,-7,0,56,0,-112,0,64,0,0,0,0,0,0,0,0},
 {1,0,-32,0,160,0,-256,0,128,0,0,0,0,0,0,0},
 {0,9,0,-120,0,432,0,-576,0,256,0,0,0,0,0},
 {-1,0,50,0,-400,0,1120,0,-1280,0,512,0,0,0,0,0},
 {0,-11,0,220,0,-1232,0,2816,0,-2816,0,1024,0,0,0,0},
 {1,0,-72,0,840,0,-3584,0,6912,0,-6144,0,2048,0,0,0},
 {0,13,0,-364,0,2912,0,-9984,0,16640,0,-13312,0,4096,0,0},
 {-1,0,98,0,-1568,0,9408,0,-26880,0,39424,0,-28672,0,8192,0},
 {0,-15,0,560,0,-6048,0,28800,0,-70400,0,92160,0,-61440,0,16384}};

// DPP add: x + dpp_move(x). All-VALU cross-lane (no LDS pipe, no lgkmcnt).
template <int C>
__device__ __forceinline__ float dppadd(float x) {
    return x + __builtin_bit_cast(float,
        __builtin_amdgcn_update_dpp(0, __builtin_bit_cast(int, x), C, 0xF, 0xF, true));
}
__device__ __forceinline__ float red_quad(float x) {      // sum over each quad
    x = dppadd<0xB1>(x); x = dppadd<0x4E>(x); return x;
}
__device__ __forceinline__ float red_wave64(float x) {    // valid in lane 63
    x = dppadd<0xB1>(x); x = dppadd<0x4E>(x); x = dppadd<0x141>(x);
    x = dppadd<0x140>(x); x = dppadd<0x142>(x); x = dppadd<0x143>(x); return x;
}
// All-lane 16-sum via mirror stages (each is a permutation => valid everywhere).
__device__ __forceinline__ float red16_all(float x) {
    x = dppadd<0xB1>(x);   // xor1 (quad perm)
    x = dppadd<0x4E>(x);   // xor2 (quad perm)
    x = dppadd<0x141>(x);  // row half mirror
    x = dppadd<0x140>(x);  // row mirror
    return x;
}

// TWO independent single-batch recurrences per block (8 waves: waves 0-3 =
// batch 2*bid, waves 4-7 = batch 2*bid+1). Each half is EXACTLY the verified
// round-6 structure (4 waves, wave-local MFMA tiling, all gates lane-local,
// writer-side parity-split x-poly, one raw barrier per step). The two halves
// share only the batch-independent Ml/g2 tables and the block barrier.
// Rationale (r6/r9 counters): the single-batch step is ~50% latency stall
// with 1-2 waves/SIMD and BOTH pipes <26% busy; per-wave work tweaks never
// moved it. Co-locating a second INDEPENDENT stream on each SIMD fills the
// stall with real issue (classic TLP) without lengthening either batch's
// critical path -- the shared barrier just phase-locks two same-cadence
// loops. Expected: step(2 batches) ~ 1.3-1.5x step(1 batch) => ~1.4x net.
__global__ __launch_bounds__(NT, 2)
void attn_lstm_decoder(const float* __restrict__ enc,   // [B,S,E]
                       const float* __restrict__ W1w,   // [S,S]
                       const float* __restrict__ W1b,   // [S]
                       const float* __restrict__ W2w,   // [S,2S]
                       const float* __restrict__ W2b,   // [S]
                       const float* __restrict__ Wih,   // [4D,E]
                       const float* __restrict__ Whh,   // [4D,D]
                       const float* __restrict__ bih,   // [4D]
                       const float* __restrict__ bhh,   // [4D]
                       float* __restrict__ out)         // [S,B,D]
{
    const int b0   = blockIdx.x * NBB;
    const int t    = threadIdx.x;
    const int tb   = t >> 8;          // batch half (0/1)
    const int tt   = t & 255;         // thread within the half
    const int ww   = tt >> 6;         // wave within the half, 0..3
    const int lane = t & 63;
    const int grp  = lane >> 4;       // 0..3: MFMA k-group
    const int nib  = lane & 15;       // MFMA n-index
    const int sub  = grp & 1;         // which 16-block of the wave's 32 ch
    const int cpy  = grp >> 1;        // redundancy copy / poly parity
    const int gl   = 32 * ww + 16 * sub + nib;   // this thread's channel
    const int b    = b0 + tb;         // this half's batch element

    __shared__ __align__(16) _Float16 hist16[NBB][2 * ND]; // f16 h dbuf per half
    __shared__ __align__(16) float xwbuf[NBB][2][8];       // 4 waves x float2
    __shared__ float A2_l[NBB][NS];
    __shared__ float e0_l[NBB][NS];
    __shared__ float e1_l[NBB][NS];
    __shared__ float g2_l[NS];        // batch-independent (half 0 writes)
    __shared__ float Ml[NN * NN];     // batch-independent (half 0 writes)
    __shared__ float2 Pn[NBB][NN];
    __shared__ float2 Vl[NBB][NN];
    __shared__ float Pm0[NBB][NN], Pm1[NBB][NN];

    // ---------------- setup (once per block, per half) ----------------
    #pragma unroll
    for (int i = tt; i < NS * NE; i += 256) {
        float v = enc[(size_t)b * (NS * NE) + i];      // coalesced
        if (i & 1) e1_l[tb][i >> 1] = v; else e0_l[tb][i >> 1] = v;
    }
    if (tb == 0) {   // tt covers exactly NN*NN = 256
        const int mi = tt >> 4, mj = tt & 15;
        const float w = (mi == 0) ? (1.0f / NN) : (2.0f / NN);
        Ml[tt] = w * __cosf((float)(mi * (2 * mj + 1)) * (PI_F / (2 * NN)));
    }
    __syncthreads();

    // w1sum rows (batch-independent, half 0 only) and w2term rows (per half):
    // 64 rows per wave.
    for (int r = 0; r < 64; ++r) {
        const int s = ww * 64 + r;
        if (tb == 0) {
            float p = W1w[s * NS + lane]       + W1w[s * NS + lane + 64]
                    + W1w[s * NS + lane + 128] + W1w[s * NS + lane + 192];
            p = red_wave64(p);
            if (lane == 63) g2_l[s] = p * (2.0f * L2E);
        }
        float qq = 0.0f;
        #pragma unroll
        for (int kk = 0; kk < 8; ++kk) {
            const int c = lane + kk * 64;
            const float ev = (c & 1) ? e1_l[tb][c >> 1] : e0_l[tb][c >> 1];
            qq = fmaf(ev, W2w[s * (2 * NS) + c], qq);
        }
        qq = red_wave64(qq);
        if (lane == 63) A2_l[tb][s] = (qq + W2b[s] + W1b[s]) * (2.0f * L2E);
    }
    __syncthreads();

    // One-time node softmax: F(y_j), one node per 16-lane group (16/half).
    {
        const int jn = 4 * ww + grp;
        const float y  = __cosf((float)(2 * jn + 1) * (PI_F / (2 * NN)));
        const float C2 = -2.0f * L2E;
        float l = 0.0f, p0 = 0.0f, p1 = 0.0f;
        #pragma unroll
        for (int k = 0; k < 16; ++k) {
            const int s = k * 16 + nib;
            const float m1 = fmaf(y, g2_l[s], A2_l[tb][s]);
            const float u  = __builtin_amdgcn_exp2f(m1);
            const float rc = __builtin_amdgcn_rcpf(u + 1.0f);
            const float e  = __builtin_amdgcn_exp2f(rc * C2);
            l += e;
            p0 = fmaf(e, e0_l[tb][s], p0);
            p1 = fmaf(e, e1_l[tb][s], p1);
        }
        l = red16_all(l); p0 = red16_all(p0); p1 = red16_all(p1);
        if (nib == 0) {
            const float rl = __builtin_amdgcn_rcpf(l);
            Pn[tb][jn] = make_float2(p0 * rl, p1 * rl);
        }
    }
    __syncthreads();

    // DCT collapse: V[i] = sum_j M[i][j]*Pn[j], 1/ND folded in (per half).
    if (tt < NN) {
        float v0 = 0.0f, v1 = 0.0f;
        #pragma unroll
        for (int j = 0; j < NN; ++j) {
            v0 = fmaf(Ml[tt * NN + j], Pn[tb][j].x, v0);
            v1 = fmaf(Ml[tt * NN + j], Pn[tb][j].y, v1);
        }
        Vl[tb][tt] = make_float2(v0 * (1.0f / ND), v1 * (1.0f / ND));
    }

    // W_hh MFMA B-fragments, WAVE-LOCAL rows (identical in both halves):
    // tile (j,s) covers gate-j rows 128*j + 32*ww + 16*s + [0,16).
    // Lane holds B[k][n]: n = nib, k = 32*kt + 8*grp + e (contiguous 8).
    f16x8 wf[4][2][4];
    #pragma unroll
    for (int j = 0; j < 4; ++j) {
        #pragma unroll
        for (int s = 0; s < 2; ++s) {
            const int row = 128 * j + 32 * ww + 16 * s + nib;
            #pragma unroll
            for (int kt = 0; kt < 4; ++kt) {
                const vf4 wa = *reinterpret_cast<const vf4*>(Whh + row * ND + 32 * kt + 8 * grp);
                const vf4 wb = *reinterpret_cast<const vf4*>(Whh + row * ND + 32 * kt + 8 * grp + 4);
                f16x8 wv;
                wv[0] = (_Float16)wa.x; wv[1] = (_Float16)wa.y;
                wv[2] = (_Float16)wa.z; wv[3] = (_Float16)wa.w;
                wv[4] = (_Float16)wb.x; wv[5] = (_Float16)wb.y;
                wv[6] = (_Float16)wb.z; wv[7] = (_Float16)wb.w;
                wf[j][s][kt] = wv;
            }
        }
    }
    // All-4-gate per-lane constants for this thread's channel gl.
    float wi0_[4], wi1_[4], bb_[4];
    #pragma unroll
    for (int j = 0; j < 4; ++j) {
        const int r = 128 * j + gl;
        wi0_[j] = Wih[r * 2 + 0];
        wi1_[j] = Wih[r * 2 + 1];
        bb_[j]  = bih[r] + bhh[r];
    }

    // zero-init both h buffers of this half
    if (tt < 2 * ND) hist16[tb][tt] = (_Float16)0.0f;
    float h_reg = 0.0f, c_reg = 0.0f;
    __syncthreads();                   // Vl visible

    // Chebyshev -> monomial: Pm[m] = sum_k V[k] * CT[k][m] (per half).
    if (tt < NN) {
        float s0 = 0.0f, s1 = 0.0f;
        #pragma unroll
        for (int k = 0; k < NN; ++k) {
            s0 = fmaf(Vl[tb][k].x, CT[k][tt], s0);
            s1 = fmaf(Vl[tb][k].y, CT[k][tt], s1);
        }
        Pm0[tb][tt] = s0; Pm1[tb][tt] = s1;
    }
    __syncthreads();                   // Pm visible

    // cpy-split coefficients: cpy=0 -> even monomials, cpy=1 -> odd.
    float cc0[8], cc1[8];
    #pragma unroll
    for (int i = 0; i < 8; ++i) {
        cc0[i] = Pm0[tb][2 * i + cpy];
        cc1[i] = Pm1[tb][2 * i + cpy];
    }

    // phaseG: this thread's half (parity cpy) of G(h) at its own f32 h;
    // wave sum over 64 lanes (32 ch x 2 parities) = the wave's x partial.
    auto phaseG = [&](float h, int pw) {
        const float h2 = h * h;
        float v0 = cc0[7], v1 = cc1[7];
        #pragma unroll
        for (int k = 6; k >= 0; --k) {
            v0 = fmaf(v0, h2, cc0[k]);
            v1 = fmaf(v1, h2, cc1[k]);
        }
        const float hsel = cpy ? h : 1.0f;
        v0 *= hsel;
        v1 *= hsel;
        v0 = red_wave64(v0); v1 = red_wave64(v1);
        if (lane == 63) {
            xwbuf[tb][pw][2 * ww + 0] = v0;
            xwbuf[tb][pw][2 * ww + 1] = v1;
        }
    };

    phaseG(0.0f, 0);       // x for step 0 (h = 0)
    __syncthreads();

    // ---------------- the recurrence (ONE barrier per step) ----------------
    for (int step = 0; step < NS; ++step) {
        const int pr = step & 1;
        const int rs = pr ^ 1;            // buffer holding h(step-1)
        const int ws = pr;                // buffer for h(step)
        const _Float16* hb = &hist16[tb][rs * ND];

        // A fragments: each 16-lane group reads the SAME 16B of h (broadcast),
        // so A[m][k] = h[k] for every m; all C rows are identical.
        const f16x8 af0 = __builtin_bit_cast(f16x8, *reinterpret_cast<const int4*>(hb + 0  + 8 * grp));
        const f16x8 af1 = __builtin_bit_cast(f16x8, *reinterpret_cast<const int4*>(hb + 32 + 8 * grp));
        const f16x8 af2 = __builtin_bit_cast(f16x8, *reinterpret_cast<const int4*>(hb + 64 + 8 * grp));
        const f16x8 af3 = __builtin_bit_cast(f16x8, *reinterpret_cast<const int4*>(hb + 96 + 8 * grp));

        // x from the 4 wave partials (broadcast read + quad reduce).
        float2 xv = *reinterpret_cast<const float2*>(&xwbuf[tb][pr][2 * (lane & 3)]);
        const float x0 = red_quad(xv.x);
        const float x1 = red_quad(xv.y);
        float bt[4];
        #pragma unroll
        for (int j = 0; j < 4; ++j)
            bt[j] = fmaf(x0, wi0_[j], fmaf(x1, wi1_[j], bb_[j]));

        // Gate matvec on the MFMA pipe: 8 independent depth-4 chains
        // (4 gates x 2 16-blocks); select on sub picks this lane's block.
        float ga[4];
        #pragma unroll
        for (int j = 0; j < 4; ++j) {
            f32x4 a0 = {0.0f, 0.0f, 0.0f, 0.0f};
            f32x4 a1 = {0.0f, 0.0f, 0.0f, 0.0f};
            a0 = __builtin_amdgcn_mfma_f32_16x16x32_f16(af0, wf[j][0][0], a0, 0, 0, 0);
            a1 = __builtin_amdgcn_mfma_f32_16x16x32_f16(af0, wf[j][1][0], a1, 0, 0, 0);
            a0 = __builtin_amdgcn_mfma_f32_16x16x32_f16(af1, wf[j][0][1], a0, 0, 0, 0);
            a1 = __builtin_amdgcn_mfma_f32_16x16x32_f16(af1, wf[j][1][1], a1, 0, 0, 0);
            a0 = __builtin_amdgcn_mfma_f32_16x16x32_f16(af2, wf[j][0][2], a0, 0, 0, 0);
            a1 = __builtin_amdgcn_mfma_f32_16x16x32_f16(af2, wf[j][1][2], a1, 0, 0, 0);
            a0 = __builtin_amdgcn_mfma_f32_16x16x32_f16(af3, wf[j][0][3], a0, 0, 0, 0);
            a1 = __builtin_amdgcn_mfma_f32_16x16x32_f16(af3, wf[j][1][3], a1, 0, 0, 0);
            ga[j] = sub ? a1[0] : a0[0];
        }

        const float gi = ga[0] + bt[0];
        const float gf = ga[1] + bt[1];
        const float gg = ga[2] + bt[2];
        const float go = ga[3] + bt[3];

        const float si = __builtin_amdgcn_rcpf(1.0f + __builtin_amdgcn_exp2f(-L2E * gi));
        const float sf = __builtin_amdgcn_rcpf(1.0f + __builtin_amdgcn_exp2f(-L2E * gf));
        const float so = __builtin_amdgcn_rcpf(1.0f + __builtin_amdgcn_exp2f(-L2E * go));
        const float tg = 1.0f - 2.0f * __builtin_amdgcn_rcpf(
            __builtin_amdgcn_exp2f(2.0f * L2E * gg) + 1.0f);
        c_reg = fmaf(sf, c_reg, si * tg);
        const float tc2 = 1.0f - 2.0f * __builtin_amdgcn_rcpf(
            __builtin_amdgcn_exp2f(2.0f * L2E * c_reg) + 1.0f);
        h_reg = so * tc2;

        // Tail: one f16 LDS write per channel (+ fire-and-forget global).
        if (cpy == 0) {
            hist16[tb][ws * ND + gl] = (_Float16)h_reg;
            out[(size_t)step * (NB * ND) + (size_t)b * ND + gl] = h_reg;  // async
        }
        phaseG(h_reg, pr ^ 1);                            // x for step k+1

        // LDS-only drain + raw barrier: global stores stay in flight.
        asm volatile("s_waitcnt lgkmcnt(0)" ::: "memory");
        __builtin_amdgcn_s_barrier();
    }
}

extern "C" void kernel_launch(void* const* d_in, const int* in_sizes, int n_in,
                              void* d_out, int out_size, void* d_ws, size_t ws_size,
                              hipStream_t stream) {
    const float* enc = (const float*)d_in[0];
    const float* W1w = (const float*)d_in[1];
    const float* W1b = (const float*)d_in[2];
    const float* W2w = (const float*)d_in[3];
    const float* W2b = (const float*)d_in[4];
    const float* Wih = (const float*)d_in[5];
    const float* Whh = (const float*)d_in[6];
    const float* bih = (const float*)d_in[7];
    const float* bhh = (const float*)d_in[8];
    attn_lstm_decoder<<<NB / NBB, NT, 0, stream>>>(enc, W1w, W1b, W2w, W2b,
                                                   Wih, Whh, bih, bhh, (float*)d_out);
}

// Round 11
// 260.808 us; speedup vs baseline: 2.6526x; 1.3607x over previous
//
#include <hip/hip_runtime.h>

#define NB 256   // batch
#define NS 256   // seq len == number of steps
#define NE 2     // encoder dim
#define ND 128   // decoder dim
#define NT 512   // threads per block (8 waves)
#define NN 16    // Chebyshev nodes/degree for the h -> context map
#define RING 32  // h-history ring depth (2 store chunks of 16)
#define SLOT 144 // padded words per fp32 ring slot (4 slices of 36)
#define SLOTH 160 // padded halfs per f16 ring slot (4 slices of 40)

typedef float vf4 __attribute__((ext_vector_type(4)));
typedef _Float16 f16x8 __attribute__((ext_vector_type(8)));
typedef float f32x4 __attribute__((ext_vector_type(4)));

constexpr float L2E = 1.4426950408889634f;  // log2(e)
constexpr float PI_F = 3.14159265358979323846f;

// Monomial coefficients of Chebyshev T_k: T_k(h) = sum_m CT[k][m] h^m (exact ints).
__device__ const float CT[16][16] = {
 {1,0,0,0,0,0,0,0,0,0,0,0,0,0,0,0},
 {0,1,0,0,0,0,0,0,0,0,0,0,0,0,0,0},
 {-1,0,2,0,0,0,0,0,0,0,0,0,0,0,0,0},
 {0,-3,0,4,0,0,0,0,0,0,0,0,0,0,0,0},
 {1,0,-8,0,8,0,0,0,0,0,0,0,0,0,0,0},
 {0,5,0,-20,0,16,0,0,0,0,0,0,0,0,0,0},
 {-1,0,18,0,-48,0,32,0,0,0,0,0,0,0,0,0},
 {0,-7,0,56,0,-112,0,64,0,0,0,0,0,0,0,0},
 {1,0,-32,0,160,0,-256,0,128,0,0,0,0,0,0,0},
 {0,9,0,-120,0,432,0,-576,0,256,0,0,0,0,0},
 {-1,0,50,0,-400,0,1120,0,-1280,0,512,0,0,0,0,0},
 {0,-11,0,220,0,-1232,0,2816,0,-2816,0,1024,0,0,0,0},
 {1,0,-72,0,840,0,-3584,0,6912,0,-6144,0,2048,0,0,0},
 {0,13,0,-364,0,2912,0,-9984,0,16640,0,-13312,0,4096,0,0},
 {-1,0,98,0,-1568,0,9408,0,-26880,0,39424,0,-28672,0,8192,0},
 {0,-15,0,560,0,-6048,0,28800,0,-70400,0,92160,0,-61440,0,16384}};

// DPP add: x + dpp_move(x). All-VALU cross-lane (no LDS pipe, no lgkmcnt).
template <int C>
__device__ __forceinline__ float dppadd(float x) {
    return x + __builtin_bit_cast(float,
        __builtin_amdgcn_update_dpp(0, __builtin_bit_cast(int, x), C, 0xF, 0xF, true));
}
// DPP move (quad_perm broadcast): returns value of quad-lane C_SEL in each quad.
template <int C>
__device__ __forceinline__ float quadbc(float x) {
    return __builtin_bit_cast(float,
        __builtin_amdgcn_update_dpp(0, __builtin_bit_cast(int, x), C, 0xF, 0xF, true));
}
__device__ __forceinline__ float red_quad(float x) {      // sum over each quad
    x = dppadd<0xB1>(x); x = dppadd<0x4E>(x); return x;
}
__device__ __forceinline__ float red_oct(float x) {       // sum over each octet
    x = dppadd<0xB1>(x); x = dppadd<0x4E>(x); x = dppadd<0x141>(x); return x;
}
__device__ __forceinline__ float red_wave64(float x) {    // valid in lane 63
    x = dppadd<0xB1>(x); x = dppadd<0x4E>(x); x = dppadd<0x141>(x);
    x = dppadd<0x140>(x); x = dppadd<0x142>(x); x = dppadd<0x143>(x); return x;
}
__device__ __forceinline__ float red_half32(float x) {    // 32-lane sums
    x = dppadd<0xB1>(x); x = dppadd<0x4E>(x); x = dppadd<0x141>(x);
    x = dppadd<0x140>(x); x = dppadd<0x142>(x); return x;
}
__device__ __forceinline__ float red_grp16(float x) {     // quads hold identical copies:
    // mirrors/bcasts add ONE copy per quad => EXACT sum over 16 quad values.
    x = dppadd<0x141>(x); x = dppadd<0x140>(x);
    x = dppadd<0x142>(x); x = dppadd<0x143>(x); return x;
}

// One block per batch element; 256-step recurrence in-block, ONE barrier/step.
// Attention collapsed (setup) to degree-15 monomial poly, quad-split.
// Gate matvec on the MFMA pipe, WAVE-LOCAL tiling: wave w's 16 MFMAs cover
// exactly the 64 gate rows {128*j + 16*w + c : j=0..3, c=0..15} its own
// threads consume. A = h broadcast => all C rows identical => every lane
// holds gate j for column lane&15 in acc[j][0]. Each thread fetches its 4
// gates with ONE ds_bpermute (select acc[lane>>4], pull from lane
// ((lane&3)<<4)|(lane>>2)) -- no LDS staging, no second barrier.
// Activations quad-split: each lane does ONE sigmoid/tanh (per-lane
// constants), 4 DPP quad-broadcasts reassemble si/sf/tg/so.
//
// SESSION NOTE (rounds 0-10): this is the measured champion (bench 262.7us,
// rocprof 210.8us). Eleven structural variants (pipe splits, wave counts,
// redundancy levels, batch packing, 2-stream TLP) all land at or above the
// ~820ns/step serial-skeleton floor: barrier + LDS h-exchange + 32
// MFMA/SIMD matvec (16x M-waste irreducible) + transcendental chain + poly
// tail. Both pipes <26% busy, HBM 2% -- a latency floor, not a roofline.
__global__ __launch_bounds__(NT, 2)
void attn_lstm_decoder(const float* __restrict__ enc,   // [B,S,E]
                       const float* __restrict__ W1w,   // [S,S]
                       const float* __restrict__ W1b,   // [S]
                       const float* __restrict__ W2w,   // [S,2S]
                       const float* __restrict__ W2b,   // [S]
                       const float* __restrict__ Wih,   // [4D,E]
                       const float* __restrict__ Whh,   // [4D,D]
                       const float* __restrict__ bih,   // [4D]
                       const float* __restrict__ bhh,   // [4D]
                       float* __restrict__ out)         // [S,B,D]
{
    const int b    = blockIdx.x;
    const int t    = threadIdx.x;
    const int wave = t >> 6;
    const int lane = t & 63;
    const int g    = t >> 2;          // d-index / row group, 0..127
    const int q    = t & 3;           // monomial residue class == this lane's gate
    const bool qb0 = q & 1;
    const bool qb1 = q & 2;
    const int grp  = lane >> 4;       // MFMA k-group 0..3
    const int nib  = lane & 15;       // MFMA n-index 0..15
    // setup-only:
    const int half = lane >> 5;
    const int idx  = lane & 31;
    const int jnode = 2 * wave + half;

    __shared__ __align__(16) float    hist[RING * SLOT];    // fp32 h ring (output)
    __shared__ __align__(16) _Float16 hist16[RING * SLOTH]; // f16 h ring (MFMA A)
    __shared__ __align__(16) float xwbuf[2][16];        // 8 waves x float2 partial x
    __shared__ float A2_l[NS];
    __shared__ float g2_l[NS];
    __shared__ float e0_l[NS];
    __shared__ float e1_l[NS];
    __shared__ float Ml[NN * NN];
    __shared__ float2 Pn[NN];
    __shared__ float2 Vl[NN];
    __shared__ float Pm0[NN], Pm1[NN];

    // ---------------- setup (once per block) ----------------
    {
        float v = enc[b * (NS * NE) + t];      // coalesced
        if (t & 1) e1_l[t >> 1] = v; else e0_l[t >> 1] = v;
    }
    if (t < NN * NN) {
        const int mi = t >> 4, mj = t & 15;
        const float w = (mi == 0) ? (1.0f / NN) : (2.0f / NN);
        Ml[t] = w * __cosf((float)(mi * (2 * mj + 1)) * (PI_F / (2 * NN)));
    }
    __syncthreads();

    // w1sum rows and w2term rows: 32 rows per wave (DPP reductions).
    for (int r = 0; r < 32; ++r) {
        const int s = wave * 32 + r;
        float p = W1w[s * NS + lane]       + W1w[s * NS + lane + 64]
                + W1w[s * NS + lane + 128] + W1w[s * NS + lane + 192];
        p = red_wave64(p);
        if (lane == 63) g2_l[s] = p * (2.0f * L2E);
        float qq = 0.0f;
        #pragma unroll
        for (int kk = 0; kk < 8; ++kk) {
            const int c = lane + kk * 64;
            const float ev = (c & 1) ? e1_l[c >> 1] : e0_l[c >> 1];
            qq = fmaf(ev, W2w[s * (2 * NS) + c], qq);
        }
        qq = red_wave64(qq);
        if (lane == 63) A2_l[s] = (qq + W2b[s] + W1b[s]) * (2.0f * L2E);
    }
    __syncthreads();

    // One-time node softmax: F(y_j) for the 16 Chebyshev nodes (2 nodes/wave).
    {
        const float y  = __cosf((float)(2 * jnode + 1) * (PI_F / (2 * NN)));
        const float C2 = -2.0f * L2E;
        float l = 0.0f, p0 = 0.0f, p1 = 0.0f;
        #pragma unroll
        for (int k = 0; k < 8; ++k) {
            const int s = k * 32 + idx;
            const float m1 = fmaf(y, g2_l[s], A2_l[s]);
            const float u  = __builtin_amdgcn_exp2f(m1);
            const float rc = __builtin_amdgcn_rcpf(u + 1.0f);
            const float e  = __builtin_amdgcn_exp2f(rc * C2);
            l += e;
            p0 = fmaf(e, e0_l[s], p0);
            p1 = fmaf(e, e1_l[s], p1);
        }
        l = red_half32(l); p0 = red_half32(p0); p1 = red_half32(p1);
        if ((lane & 31) == 31) {
            const float rl = __builtin_amdgcn_rcpf(l);
            Pn[jnode] = make_float2(p0 * rl, p1 * rl);
        }
    }
    __syncthreads();

    // DCT collapse: V[i] = sum_j M[i][j]*Pn[j], 1/ND folded in.
    if (t < NN) {
        float v0 = 0.0f, v1 = 0.0f;
        #pragma unroll
        for (int j = 0; j < NN; ++j) {
            v0 = fmaf(Ml[t * NN + j], Pn[j].x, v0);
            v1 = fmaf(Ml[t * NN + j], Pn[j].y, v1);
        }
        Vl[t] = make_float2(v0 * (1.0f / ND), v1 * (1.0f / ND));
    }

    // W_hh MFMA B-fragments, WAVE-LOCAL rows: tile rt (= gate index) covers
    // rows 128*rt + 16*wave + [0,16). Lane holds B[k][n]: n = nib,
    // k = 32*kt + 8*grp + e (contiguous 8, packed little-endian).
    f16x8 wf[4][4];
    #pragma unroll
    for (int rt = 0; rt < 4; ++rt) {
        const int row = 128 * rt + 16 * wave + nib;
        #pragma unroll
        for (int kt = 0; kt < 4; ++kt) {
            const vf4 wa = *reinterpret_cast<const vf4*>(Whh + row * ND + 32 * kt + 8 * grp);
            const vf4 wb = *reinterpret_cast<const vf4*>(Whh + row * ND + 32 * kt + 8 * grp + 4);
            f16x8 wv;
            wv[0] = (_Float16)wa.x; wv[1] = (_Float16)wa.y;
            wv[2] = (_Float16)wa.z; wv[3] = (_Float16)wa.w;
            wv[4] = (_Float16)wb.x; wv[5] = (_Float16)wb.y;
            wv[6] = (_Float16)wb.z; wv[7] = (_Float16)wb.w;
            wf[rt][kt] = wv;
        }
    }
    // This lane's gate (= q) constants for row 128*q + g.
    const int rq = 128 * q + g;
    const float wiq0 = Wih[rq * 2 + 0];
    const float wiq1 = Wih[rq * 2 + 1];
    const float bbq  = bih[rq] + bhh[rq];
    // activation: act = cA1 * rcp(1 + exp2(sA * x)) + cA0
    //   sigmoid (q=0,1,3): sA=-L2E, cA1=1, cA0=0 ; tanh (q=2): sA=2*L2E, cA1=-2, cA0=1
    const float sA  = (q == 2) ? (2.0f * L2E) : (-L2E);
    const float cA1 = (q == 2) ? -2.0f : 1.0f;
    const float cA0 = (q == 2) ? 1.0f : 0.0f;
    // bpermute source lane: gate lane&3 at column lane>>2 lives (as col s&15,
    // reg0, selected by s>>4) in lane s = ((lane&3)<<4) | (lane>>2).
    const int bidx = ((((lane & 3) << 4) | (lane >> 2)) << 2);

    // zero-init ring slot 31 (input of step 0) in both rings
    if (t < ND) {
        hist[31 * SLOT + 36 * (t >> 5) + (t & 31)] = 0.0f;
        hist16[31 * SLOTH + 40 * (t >> 5) + (t & 31)] = (_Float16)0.0f;
    }
    float h_reg = 0.0f, c_reg = 0.0f;
    __syncthreads();                   // Vl visible

    // Chebyshev -> monomial: Pm[m] = sum_k V[k] * CT[k][m].
    if (t < NN) {
        float s0 = 0.0f, s1 = 0.0f;
        #pragma unroll
        for (int k = 0; k < NN; ++k) {
            s0 = fmaf(Vl[k].x, CT[k][t], s0);
            s1 = fmaf(Vl[k].y, CT[k][t], s1);
        }
        Pm0[t] = s0; Pm1[t] = s1;
    }
    __syncthreads();                   // Pm visible

    // Per-lane residue-class coefficients: G_e(h) = sum_q h^q * Q_q(h^4).
    float Q0[4], Q1[4];
    #pragma unroll
    for (int i = 0; i < 4; ++i) { Q0[i] = Pm0[4 * i + q]; Q1[i] = Pm1[4 * i + q]; }

    // phaseG: quad-split monomial eval; red_quad reassembles G(h), then
    // mirror-reduce over the 16 quads. lane63 writes this wave's partial.
    auto phaseG = [&](float h, int pw) {
        const float h2 = h * h;
        const float h3 = h2 * h;
        const float h4 = h2 * h2;
        const float hq = qb1 ? (qb0 ? h3 : h2) : (qb0 ? h : 1.0f);
        float a0 = fmaf(Q0[3], h4, Q0[2]);
        a0 = fmaf(a0, h4, Q0[1]);
        a0 = fmaf(a0, h4, Q0[0]);
        float a1 = fmaf(Q1[3], h4, Q1[2]);
        a1 = fmaf(a1, h4, Q1[1]);
        a1 = fmaf(a1, h4, Q1[0]);
        a0 *= hq;
        a1 *= hq;
        a0 = red_quad(a0);  a1 = red_quad(a1);     // reassemble G(h_g)
        a0 = red_grp16(a0); a1 = red_grp16(a1);    // sum over the wave's 16 g
        if (lane == 63) {
            xwbuf[pw][2 * wave + 0] = a0;
            xwbuf[pw][2 * wave + 1] = a1;
        }
    };

    phaseG(0.0f, 0);       // x for step 0 (h = 0)
    __syncthreads();

    // ---------------- the recurrence (ONE barrier per step) ----------------
    for (int step = 0; step < NS; ++step) {
        const int pr = step & 1;
        const int rs = (step + RING - 1) & (RING - 1);   // slot holding h(step-1)
        const int ws = step & (RING - 1);                // slot for h(step)

        // A fragments: each 16-lane group reads the SAME 16B of h (broadcast),
        // so A[m][k] = h[k] for every m; all C rows are identical.
        f16x8 af[4];
        const _Float16* hsl = &hist16[rs * SLOTH + 8 * grp];
        #pragma unroll
        for (int kt = 0; kt < 4; ++kt)
            af[kt] = __builtin_bit_cast(f16x8,
                *reinterpret_cast<const int4*>(hsl + 40 * kt));

        // Independent work while A loads land: x partials + chunk store.
        float2 xv = *reinterpret_cast<const float2*>(&xwbuf[pr][2 * (lane & 7)]);

        // Chunk store (every 16 steps, at step TOP): steps step-16..step-1.
        if ((step & 15) == 0 && step > 0) {
            const int sb  = (step - 16) & (RING - 1);
            const int k   = t >> 5;
            const int l32 = t & 31;
            const int w   = 4 * l32;
            const vf4 v = *reinterpret_cast<const vf4*>(
                &hist[(sb + k) * SLOT + 36 * (w >> 5) + (w & 31)]);
            *reinterpret_cast<vf4*>(
                &out[(size_t)(step - 16 + k) * (NB * ND) + b * ND + w]) = v;
        }

        float x0 = red_oct(xv.x);
        float x1 = red_oct(xv.y);

        // Gate matvec on the MFMA pipe: 4 independent chains of 4.
        f32x4 acc[4];
        #pragma unroll
        for (int rt = 0; rt < 4; ++rt) {
            f32x4 a = {0.0f, 0.0f, 0.0f, 0.0f};
            #pragma unroll
            for (int kt = 0; kt < 4; ++kt)
                a = __builtin_amdgcn_mfma_f32_16x16x32_f16(af[kt], wf[rt][kt], a, 0, 0, 0);
            acc[rt] = a;
        }

        // Wave-local gate fetch: select this lane's served gate (lane>>4),
        // then one bpermute delivers gate q at column g to every thread.
        const float a01 = (lane & 16) ? acc[1][0] : acc[0][0];
        const float a23 = (lane & 16) ? acc[3][0] : acc[2][0];
        const float av  = (lane & 32) ? a23 : a01;
        const float myg = __builtin_bit_cast(float,
            __builtin_amdgcn_ds_bpermute(bidx, __builtin_bit_cast(int, av)));

        // Quad-split activation: one transcendental pair per lane.
        const float gq  = myg + fmaf(x0, wiq0, fmaf(x1, wiq1, bbq));
        const float act = fmaf(cA1,
            __builtin_amdgcn_rcpf(1.0f + __builtin_amdgcn_exp2f(sA * gq)), cA0);
        const float si = quadbc<0x00>(act);
        const float sf = quadbc<0x55>(act);
        const float tg = quadbc<0xAA>(act);
        const float so = quadbc<0xFF>(act);

        c_reg = fmaf(sf, c_reg, si * tg);
        const float tc2 = 1.0f - 2.0f * __builtin_amdgcn_rcpf(
            __builtin_amdgcn_exp2f(2.0f * L2E * c_reg) + 1.0f);
        h_reg = so * tc2;

        if (q == 0) {
            hist[ws * SLOT + 36 * (g >> 5) + (g & 31)] = h_reg;
            hist16[ws * SLOTH + 40 * (g >> 5) + (g & 31)] = (_Float16)h_reg;
        }
        phaseG(h_reg, pr ^ 1);                            // x for step k+1

        __syncthreads();                                  // h ring + x partials
    }

    // Tail: store the final chunk (steps 240..255, ring slots 16..31).
    {
        const int k   = t >> 5;
        const int l32 = t & 31;
        const int w   = 4 * l32;
        const vf4 v = *reinterpret_cast<const vf4*>(
            &hist[(16 + k) * SLOT + 36 * (w >> 5) + (w & 31)]);
        *reinterpret_cast<vf4*>(
            &out[(size_t)(240 + k) * (NB * ND) + b * ND + w]) = v;
    }
}

extern "C" void kernel_launch(void* const* d_in, const int* in_sizes, int n_in,
                              void* d_out, int out_size, void* d_ws, size_t ws_size,
                              hipStream_t stream) {
    const float* enc = (const float*)d_in[0];
    const float* W1w = (const float*)d_in[1];
    const float* W1b = (const float*)d_in[2];
    const float* W2w = (const float*)d_in[3];
    const float* W2b = (const float*)d_in[4];
    const float* Wih = (const float*)d_in[5];
    const float* Whh = (const float*)d_in[6];
    const float* bih = (const float*)d_in[7];
    const float* bhh = (const float*)d_in[8];
    attn_lstm_decoder<<<NB, NT, 0, stream>>>(enc, W1w, W1b, W2w, W2b,
                                             Wih, Whh, bih, bhh, (float*)d_out);
}